// Round 21
// baseline (758.239 us; speedup 1.0000x reference)
//
#include <hip/hip_runtime.h>

using u16 = unsigned short;
using u32 = unsigned int;
typedef __attribute__((ext_vector_type(8))) short s16x8;
typedef __attribute__((ext_vector_type(4))) float f32x4;

typedef uint4   __attribute__((may_alias)) uint4a;
typedef ushort4 __attribute__((may_alias)) ushort4a;
typedef float4  __attribute__((may_alias)) float4a;
typedef u16     __attribute__((may_alias)) u16a;
typedef s16x8   __attribute__((may_alias)) s16x8a;

#define D_ 1024
#define H_ 4
#define B_ 4
#define S_ 2048
#define M_ 8192  /* B_*S_ */

__device__ __forceinline__ float bf2f(u16 u) { return __uint_as_float(((u32)u) << 16); }
__device__ __forceinline__ u16 f2bf(float f) {
  u32 b = __float_as_uint(f);
  return (u16)((b + 0x7fffu + ((b >> 16) & 1u)) >> 16);
}

__device__ __forceinline__ void gload_lds16(const u16* g, u16* l) {
  __builtin_amdgcn_global_load_lds(
      (const __attribute__((address_space(1))) void*)g,
      (__attribute__((address_space(3))) void*)l, 16, 0, 0);
}

#define FENCE asm volatile("" ::: "memory")
#define BAR do { FENCE; __builtin_amdgcn_s_barrier(); FENCE; } while (0)
#define VMC4 asm volatile("s_waitcnt vmcnt(4)" ::: "memory")
#define VMC2 asm volatile("s_waitcnt vmcnt(2)" ::: "memory")

// XCD-bijective swizzle + 4x4 quad decomposition.
// Requires nwg%16==0, (gx*gz)%4==0, gy%4==0 (all grids verified, incl. 4x32x3).
__device__ __forceinline__ void swz_decomp(int& x, int& y, int& z) {
  const int gx = gridDim.x, gy = gridDim.y;
  const int nwg = gx * gy * gridDim.z;
  const int flat = (blockIdx.z * gy + blockIdx.y) * gx + blockIdx.x;
  const int swz = (flat & 7) * (nwg >> 3) + (flat >> 3);
  const int t = swz >> 4, i = swz & 15;
  const int tiles_X = (gx * gridDim.z) >> 2;
  const int X = (t % tiles_X) * 4 + (i & 3);
  y = (t / tiles_X) * 4 + (i >> 2);
  z = X / gx;
  x = X % gx;
}

// ---------------- f32 -> bf16 convert ----------------
__global__ __launch_bounds__(256) void cvt_f32_bf16(const float* __restrict__ in,
                                                    u16* __restrict__ out, long n4) {
  long stride = (long)gridDim.x * blockDim.x;
  for (long i = (long)blockIdx.x * blockDim.x + threadIdx.x; i < n4; i += stride) {
    float4 v = ((const float4a*)in)[i];
    ushort4 o;
    o.x = f2bf(v.x); o.y = f2bf(v.y); o.z = f2bf(v.z); o.w = f2bf(v.w);
    ((ushort4a*)out)[i] = o;
  }
}

// ------------- transpose-convert: out[z][n][k] = bf16(in[z][k][n]) -------------
__global__ __launch_bounds__(256) void tcvt(const float* __restrict__ in,
                                            u16* __restrict__ out, int K, int N,
                                            long s_in, long s_out) {
  __shared__ float t[32][33];
  const int z = blockIdx.z;
  in += (long)z * s_in;
  out += (long)z * s_out;
  const int n0 = blockIdx.x * 32, k0 = blockIdx.y * 32;
  const int tx = threadIdx.x & 31, ty = threadIdx.x >> 5;
#pragma unroll
  for (int i = 0; i < 32; i += 8) t[ty + i][tx] = in[(long)(k0 + ty + i) * N + n0 + tx];
  __syncthreads();
#pragma unroll
  for (int i = 0; i < 32; i += 8)
    out[(long)(n0 + ty + i) * K + k0 + tx] = f2bf(t[tx][ty + i]);
}

// ------------- concat biases ----
__global__ __launch_bounds__(256) void biascat(const float* __restrict__ bq,
                                               const float* __restrict__ bk,
                                               const float* __restrict__ bv,
                                               float* __restrict__ o) {
  int i = blockIdx.x * 256 + threadIdx.x;  // grid 48
  float v = (i < 4096) ? bq[i] : ((i < 8192) ? bk[i - 4096] : bv[i - 8192]);
  o[i] = v;
}

// ============ shared MFMA fragment helpers ============
__device__ __forceinline__ s16x8 lds_frag(const u16* buf, int r, int jc) {
  return *(const s16x8a*)&buf[(((r << 3) + (jc ^ (r & 7)))) << 3];
}
__device__ __forceinline__ void readA(const u16* Abuf, int q, int wr, int lane, s16x8 (&afr)[2][2]) {
#pragma unroll
  for (int il = 0; il < 2; ++il)
#pragma unroll
    for (int s = 0; s < 2; ++s)
      afr[il][s] = lds_frag(Abuf, wr * 128 + (q * 2 + il) * 16 + (lane & 15), 4 * s + (lane >> 4));
}

// ============ 256x256 8-phase body (r5-proven) — XCD-swizzled ======
// MODE 1: scores exp + dpart partials.
// MODE 4: QKV fused — z=0 Q(+bias), z=1 K(+bias+4096), z=2 V transposed(+bias+8192).
__device__ __forceinline__ void readB256(const u16* Bbuf, int wc, int lane, s16x8 (&bfr)[4][2]) {
#pragma unroll
  for (int j = 0; j < 4; ++j)
#pragma unroll
    for (int s = 0; s < 2; ++s)
      bfr[j][s] = lds_frag(Bbuf, wc * 64 + j * 16 + (lane & 15), 4 * s + (lane >> 4));
}
__device__ __forceinline__ void mfma_q256(const s16x8 (&afr)[2][2], const s16x8 (&bfr)[4][2],
                                          f32x4 (&acc)[8][4], int q) {
  __builtin_amdgcn_s_setprio(1);
#pragma unroll
  for (int s = 0; s < 2; ++s)
#pragma unroll
    for (int il = 0; il < 2; ++il)
#pragma unroll
      for (int j = 0; j < 4; ++j)
        acc[q * 2 + il][j] =
            __builtin_amdgcn_mfma_f32_16x16x32_bf16(afr[il][s], bfr[j][s], acc[q * 2 + il][j], 0, 0, 0);
  __builtin_amdgcn_s_setprio(0);
}

template <int MODE>
__device__ __forceinline__ void g256_body(
    const u16* __restrict__ A, const u16* __restrict__ Bm, u16* __restrict__ Cp,
    const float* __restrict__ bias, const float* __restrict__ bias2,
    float* __restrict__ dpart, int ldc, long sA, long sB, long sC) {
  __shared__ u16 Al[2][16384];
  __shared__ u16 Bl[2][16384];
  int bx, by, z;
  swz_decomp(bx, by, z);  // XCD-bijective block mapping
  A += (long)z * sA;
  Bm += (long)z * sB;
  const long coff = (long)z * sC;
  const int bm = by * 256, bn = bx * 256;
  const int tid = threadIdx.x;
  const int lane = tid & 63;
  const int w = tid >> 6;
  const int wr = w >> 2, wc = w & 3;
  f32x4 acc[8][4] = {};
  const int nt2 = D_ >> 7;

  auto stage = [&](const u16* src, int b0, u16* lbuf, int h, int kt) {
    const int k0 = kt << 6;
#pragma unroll
    for (int it = 0; it < 2; ++it) {
      int c = w * 128 + it * 64 + lane;
      int row = h * 128 + (c >> 3);
      int j = (c & 7) ^ (row & 7);
      gload_lds16(src + (long)(b0 + row) * D_ + (k0 + j * 8),
                  lbuf + ((h * 1024 + w * 128 + it * 64) << 3));
    }
  };

  stage(A, bm, Al[0], 0, 0);
  stage(A, bm, Al[0], 1, 0);
  stage(Bm, bn, Bl[0], 0, 0);
  stage(Bm, bn, Bl[0], 1, 0);
  stage(Bm, bn, Bl[1], 0, 1);
  stage(Bm, bn, Bl[1], 1, 1);
  VMC4;
  BAR;

  s16x8 bfr[4][2];
  for (int i2 = 0; i2 < nt2; ++i2) {
    const int t = i2 * 2;
    s16x8 afr[2][2];
    readB256(Bl[0], wc, lane, bfr);
    readA(Al[0], 0, wr, lane, afr);
    stage(A, bm, Al[1], 0, t + 1);
    BAR;
    mfma_q256(afr, bfr, acc, 0);
    BAR;
    readA(Al[0], 1, wr, lane, afr);
    stage(A, bm, Al[1], 1, t + 1);
    BAR;
    mfma_q256(afr, bfr, acc, 1);
    BAR;
    readA(Al[0], 2, wr, lane, afr);
    stage(Bm, bn, Bl[0], 0, t + 2);
    BAR;
    mfma_q256(afr, bfr, acc, 2);
    BAR;
    readA(Al[0], 3, wr, lane, afr);
    stage(Bm, bn, Bl[0], 1, t + 2);
    BAR;
    mfma_q256(afr, bfr, acc, 3);
    VMC4;
    BAR;
    readB256(Bl[1], wc, lane, bfr);
    readA(Al[1], 0, wr, lane, afr);
    stage(A, bm, Al[0], 0, t + 2);
    BAR;
    mfma_q256(afr, bfr, acc, 0);
    BAR;
    readA(Al[1], 1, wr, lane, afr);
    stage(A, bm, Al[0], 1, t + 2);
    BAR;
    mfma_q256(afr, bfr, acc, 1);
    BAR;
    readA(Al[1], 2, wr, lane, afr);
    stage(Bm, bn, Bl[1], 0, t + 3);
    BAR;
    mfma_q256(afr, bfr, acc, 2);
    BAR;
    readA(Al[1], 3, wr, lane, afr);
    stage(Bm, bn, Bl[1], 1, t + 3);
    BAR;
    mfma_q256(afr, bfr, acc, 3);
    VMC4;
    BAR;
  }

  if (MODE == 4) {
    // QKV fused: bb indexes the contiguous [bq|bk|bv] block
    const float* bb = bias + z * 4096;
    if (z == 2) {
      // V transposed: Vt[b][e][t] (4 consecutive m = 4 consecutive t -> ushort4)
#pragma unroll
      for (int i = 0; i < 8; i++) {
        int mbase = bm + wr * 128 + i * 16 + ((lane >> 4) << 2);
#pragma unroll
        for (int j = 0; j < 4; j++) {
          int n = bn + wc * 64 + j * 16 + (lane & 15);
          float bv = bb[n];
          ushort4 o;
          o.x = f2bf(acc[i][j][0] + bv);
          o.y = f2bf(acc[i][j][1] + bv);
          o.z = f2bf(acc[i][j][2] + bv);
          o.w = f2bf(acc[i][j][3] + bv);
          long idx = coff + (long)(mbase >> 11) * ((long)D_ * S_) + (long)n * S_ + (mbase & 2047);
          *(ushort4a*)&((u16a*)Cp)[idx] = o;
        }
      }
    } else {
#pragma unroll
      for (int i = 0; i < 8; i++) {
        int mbase = bm + wr * 128 + i * 16 + ((lane >> 4) << 2);
#pragma unroll
        for (int j = 0; j < 4; j++) {
          int n = bn + wc * 64 + j * 16 + (lane & 15);
          float bv = bb[n];
#pragma unroll
          for (int r = 0; r < 4; r++)
            ((u16a*)Cp)[coff + (long)(mbase + r) * ldc + n] = f2bf(acc[i][j][r] + bv);
        }
      }
    }
  } else {
    // MODE 1: scores exp + per-row partials
#pragma unroll
    for (int i = 0; i < 8; i++) {
      int mbase = bm + wr * 128 + i * 16 + ((lane >> 4) << 2);
#pragma unroll
      for (int r = 0; r < 4; r++) {
        const int mm = mbase + r;
        float rowsum = 0.f;
#pragma unroll
        for (int j = 0; j < 4; j++) {
          int n = bn + wc * 64 + j * 16 + (lane & 15);
          float e = __expf(acc[i][j][r] * 0.03125f);
          ((u16a*)Cp)[coff + (long)mm * ldc + n] = f2bf(e);
          rowsum += e;
        }
        rowsum += __shfl_xor(rowsum, 1, 64);
        rowsum += __shfl_xor(rowsum, 2, 64);
        rowsum += __shfl_xor(rowsum, 4, 64);
        rowsum += __shfl_xor(rowsum, 8, 64);
        if ((lane & 15) == 0)
          dpart[((long)z * 32 + (bx * 4 + wc)) * S_ + mm] = rowsum;
      }
    }
  }
}

__global__ __launch_bounds__(512, 2) void kQKV(
    const u16* __restrict__ A, const u16* __restrict__ Bm, u16* __restrict__ Cp,
    const float* __restrict__ bias, const float* __restrict__ bias2,
    float* __restrict__ dpart, int ldc, long sA, long sB, long sC) {
  g256_body<4>(A, Bm, Cp, bias, bias2, dpart, ldc, sA, sB, sC);
}
__global__ __launch_bounds__(512, 2) void kSC(
    const u16* __restrict__ A, const u16* __restrict__ Bm, u16* __restrict__ Cp,
    const float* __restrict__ bias, const float* __restrict__ bias2,
    float* __restrict__ dpart, int ldc, long sA, long sB, long sC) {
  g256_body<1>(A, Bm, Cp, bias, bias2, dpart, ldc, sA, sB, sC);
}

// ============ 256x128 4-phase body — kPV / kW1a / kW1b / kW2 ============
// 16 MFMA per barrier pair; XCD-swizzled. Stage plan per K-tile pair:
// P1: A(t+1)x2; P2: B(t+2) +VMC2; P3: A(t+2)x2; P4: B(t+3) +VMC2.
// OUT_MODE: 0 f32+bias, 1 bf16+bias, 5 PV-normalize (sinv from dpart), 6 bf16 RMW.
__device__ __forceinline__ void readB128(const u16* Bbuf, int wc, int lane, s16x8 (&bfr)[2][2]) {
#pragma unroll
  for (int j = 0; j < 2; ++j)
#pragma unroll
    for (int s = 0; s < 2; ++s)
      bfr[j][s] = lds_frag(Bbuf, wc * 32 + j * 16 + (lane & 15), 4 * s + (lane >> 4));
}
__device__ __forceinline__ void mfma_q128(const s16x8 (&afr)[2][2], const s16x8 (&bfr)[2][2],
                                          f32x4 (&acc)[8][2], int q) {
#pragma unroll
  for (int s = 0; s < 2; ++s)
#pragma unroll
    for (int il = 0; il < 2; ++il)
#pragma unroll
      for (int j = 0; j < 2; ++j)
        acc[q * 2 + il][j] =
            __builtin_amdgcn_mfma_f32_16x16x32_bf16(afr[il][s], bfr[j][s], acc[q * 2 + il][j], 0, 0, 0);
}

template <int OUT_MODE, int HAS_BIAS>
__device__ __forceinline__ void g256n_body(
    const u16* __restrict__ A, const u16* __restrict__ Bm, void* __restrict__ Cp,
    const float* __restrict__ bias, float* __restrict__ dpart,
    int K, int lda, int ldb, int ldc, long sA, long sB, long sC, float scale) {
  __shared__ u16 Al[2][16384];  // 2 x 32 KB: 256 rows x 64 k
  __shared__ u16 Bl[2][8192];   // 2 x 16 KB: 128 rows x 64 k
  __shared__ float sinv[256];
  int bx, by, z;
  swz_decomp(bx, by, z);
  A += (long)z * sA;
  Bm += (long)z * sB;
  const long coff = (long)z * sC;
  const int bm = by * 256, bn = bx * 128;
  const int tid = threadIdx.x;
  const int lane = tid & 63;
  const int w = tid >> 6;
  const int wr = w >> 2, wc = w & 3;  // per-wave 128 rows x 32 cols
  f32x4 acc[8][2] = {};
  const int nt2 = K >> 7;

  auto stageA = [&](u16* Abuf, int h, int kt) {
    const int k0 = kt << 6;
#pragma unroll
    for (int it = 0; it < 2; ++it) {
      int c = w * 128 + it * 64 + lane;
      int row = h * 128 + (c >> 3);
      int j = (c & 7) ^ (row & 7);
      gload_lds16(A + (long)(bm + row) * lda + (k0 + j * 8),
                  Abuf + ((h * 1024 + w * 128 + it * 64) << 3));
    }
  };
  auto stageB = [&](u16* Bbuf, int kt) {
    const int k0 = kt << 6;
#pragma unroll
    for (int it = 0; it < 2; ++it) {
      int c = w * 128 + it * 64 + lane;
      int row = c >> 3;
      int j = (c & 7) ^ (row & 7);
      gload_lds16(Bm + (long)(bn + row) * ldb + (k0 + j * 8),
                  Bbuf + ((w * 128 + it * 64) << 3));
    }
  };

  // prologue: A0<-t0 (2 calls), B0<-t0, B1<-t1; VMC2 leaves B1 in flight
  stageA(Al[0], 0, 0);
  stageA(Al[0], 1, 0);
  stageB(Bl[0], 0);
  stageB(Bl[1], 1);
  VMC2;
  BAR;

  s16x8 bfr[2][2];
  for (int i2 = 0; i2 < nt2; ++i2) {
    const int t = i2 * 2;
    s16x8 afrA[2][2], afrB[2][2];
    // P1: tile t quads 0,1 from buf0; stage A(t+1)
    readB128(Bl[0], wc, lane, bfr);
    readA(Al[0], 0, wr, lane, afrA);
    readA(Al[0], 1, wr, lane, afrB);
    stageA(Al[1], 0, t + 1);
    stageA(Al[1], 1, t + 1);
    BAR;
    __builtin_amdgcn_s_setprio(1);
    mfma_q128(afrA, bfr, acc, 0);
    mfma_q128(afrB, bfr, acc, 1);
    __builtin_amdgcn_s_setprio(0);
    BAR;
    // P2: tile t quads 2,3; stage B(t+2)
    readA(Al[0], 2, wr, lane, afrA);
    readA(Al[0], 3, wr, lane, afrB);
    stageB(Bl[0], t + 2);
    BAR;
    __builtin_amdgcn_s_setprio(1);
    mfma_q128(afrA, bfr, acc, 2);
    mfma_q128(afrB, bfr, acc, 3);
    __builtin_amdgcn_s_setprio(0);
    VMC2;  // leave B0(t+2) in flight
    BAR;
    // P3: tile t+1 quads 0,1 from buf1; stage A(t+2)
    readB128(Bl[1], wc, lane, bfr);
    readA(Al[1], 0, wr, lane, afrA);
    readA(Al[1], 1, wr, lane, afrB);
    stageA(Al[0], 0, t + 2);
    stageA(Al[0], 1, t + 2);
    BAR;
    __builtin_amdgcn_s_setprio(1);
    mfma_q128(afrA, bfr, acc, 0);
    mfma_q128(afrB, bfr, acc, 1);
    __builtin_amdgcn_s_setprio(0);
    BAR;
    // P4: tile t+1 quads 2,3; stage B(t+3)
    readA(Al[1], 2, wr, lane, afrA);
    readA(Al[1], 3, wr, lane, afrB);
    stageB(Bl[1], t + 3);
    BAR;
    __builtin_amdgcn_s_setprio(1);
    mfma_q128(afrA, bfr, acc, 2);
    mfma_q128(afrB, bfr, acc, 3);
    __builtin_amdgcn_s_setprio(0);
    VMC2;  // leave B1(t+3) in flight
    BAR;
  }

  if (OUT_MODE == 5) {
    if (tid < 256) {
      const int row = bm + tid;
      float s = 0.f;
#pragma unroll
      for (int p = 0; p < 32; ++p) s += dpart[((long)z * 32 + p) * S_ + row];
      sinv[tid] = 1.0f / s;
    }
    __syncthreads();
#pragma unroll
    for (int i = 0; i < 8; i++) {
      int mloc = wr * 128 + i * 16 + ((lane >> 4) << 2);
      float inv[4];
#pragma unroll
      for (int r = 0; r < 4; r++) inv[r] = sinv[mloc + r];
#pragma unroll
      for (int j = 0; j < 2; j++) {
        int n = bn + wc * 32 + j * 16 + (lane & 15);
#pragma unroll
        for (int r = 0; r < 4; r++) {
          ((u16a*)Cp)[coff + (long)(bm + mloc + r) * ldc + n] = f2bf(acc[i][j][r] * inv[r]);
        }
      }
    }
    return;
  }
#pragma unroll
  for (int i = 0; i < 8; i++) {
    int mbase = bm + wr * 128 + i * 16 + ((lane >> 4) << 2);
#pragma unroll
    for (int j = 0; j < 2; j++) {
      int n = bn + wc * 32 + j * 16 + (lane & 15);
      float bv = 0.f;
      if (HAS_BIAS) bv = bias[n];
#pragma unroll
      for (int r = 0; r < 4; r++) {
        float v = acc[i][j][r] * scale + bv;
        long idx = coff + (long)(mbase + r) * ldc + n;
        if (OUT_MODE == 1) {
          ((u16a*)Cp)[idx] = f2bf(v);
        } else if (OUT_MODE == 6) {
          u16a* Cb = (u16a*)Cp;
          Cb[idx] = f2bf(bf2f(Cb[idx]) + v);
        } else {
          ((float*)Cp)[idx] = v;
        }
      }
    }
  }
}

#define G256N_ARGS \
    const u16* __restrict__ A, const u16* __restrict__ Bm, void* __restrict__ Cp, \
    const float* __restrict__ bias, float* __restrict__ dpart, \
    int K, int lda, int ldb, int ldc, long sA, long sB, long sC, float scale
#define G256N_FWD A, Bm, Cp, bias, dpart, K, lda, ldb, ldc, sA, sB, sC, scale

__global__ __launch_bounds__(512, 2) void kPV(G256N_ARGS)  { g256n_body<5, 0>(G256N_FWD); }
__global__ __launch_bounds__(512, 2) void kW1a(G256N_ARGS) { g256n_body<1, 1>(G256N_FWD); }
__global__ __launch_bounds__(512, 2) void kW1b(G256N_ARGS) { g256n_body<6, 0>(G256N_FWD); }
__global__ __launch_bounds__(512, 2) void kW2(G256N_ARGS)  { g256n_body<0, 1>(G256N_FWD); }

// ---------------- LayerNorm over 1024; RBF: residual in bf16 ----------------
template <int RBF>
__global__ __launch_bounds__(256) void ln_kernel(
    const float* __restrict__ X, const void* __restrict__ R,
    const float* __restrict__ g, const float* __restrict__ be,
    float* __restrict__ Y, u16* __restrict__ Yb) {
  const long row = blockIdx.x;
  const int t = threadIdx.x, lane = t & 63, w = t >> 6;
  const long base = row * 1024 + t * 4;
  float4 a = *(const float4a*)(X + base);
  float r0, r1, r2, r3;
  if (RBF) {
    ushort4 rb = *(const ushort4a*)((const u16*)R + base);
    r0 = bf2f(rb.x); r1 = bf2f(rb.y); r2 = bf2f(rb.z); r3 = bf2f(rb.w);
  } else {
    float4 b = *(const float4a*)((const float*)R + base);
    r0 = b.x; r1 = b.y; r2 = b.z; r3 = b.w;
  }
  float v0 = a.x + r0, v1 = a.y + r1, v2 = a.z + r2, v3 = a.w + r3;
  float s = v0 + v1 + v2 + v3;
  float q = v0 * v0 + v1 * v1 + v2 * v2 + v3 * v3;
#pragma unroll
  for (int o = 32; o > 0; o >>= 1) { s += __shfl_xor(s, o, 64); q += __shfl_xor(q, o, 64); }
  __shared__ float rs[4], rq[4];
  if (lane == 0) { rs[w] = s; rq[w] = q; }
  __syncthreads();
  s = rs[0] + rs[1] + rs[2] + rs[3];
  q = rq[0] + rq[1] + rq[2] + rq[3];
  const float mu = s * (1.f / 1024.f);
  const float var = q * (1.f / 1024.f) - mu * mu;
  const float rstd = rsqrtf(var + 1e-5f);
  float4 gv = *(const float4a*)(g + t * 4);
  float4 bv = *(const float4a*)(be + t * 4);
  float o0 = (v0 - mu) * rstd * gv.x + bv.x;
  float o1 = (v1 - mu) * rstd * gv.y + bv.y;
  float o2 = (v2 - mu) * rstd * gv.z + bv.z;
  float o3 = (v3 - mu) * rstd * gv.w + bv.w;
  float4 o4; o4.x = o0; o4.y = o1; o4.z = o2; o4.w = o3;
  *(float4a*)(Y + base) = o4;
  if (Yb) {
    ushort4 ob; ob.x = f2bf(o0); ob.y = f2bf(o1); ob.z = f2bf(o2); ob.w = f2bf(o3);
    *(ushort4a*)(Yb + base) = ob;
  }
}

extern "C" void kernel_launch(void* const* d_in, const int* in_sizes, int n_in,
                              void* d_out, int out_size, void* d_ws, size_t ws_size,
                              hipStream_t stream) {
  const float* x   = (const float*)d_in[0];
  const float* Wq  = (const float*)d_in[1];
  const float* bq  = (const float*)d_in[2];
  const float* Wk  = (const float*)d_in[3];
  const float* bk  = (const float*)d_in[4];
  const float* Wv  = (const float*)d_in[5];
  const float* bv  = (const float*)d_in[6];
  const float* W1  = (const float*)d_in[7];
  const float* b1  = (const float*)d_in[8];
  const float* g1  = (const float*)d_in[9];
  const float* be1 = (const float*)d_in[10];
  const float* W2  = (const float*)d_in[11];
  const float* b2  = (const float*)d_in[12];
  const float* g2  = (const float*)d_in[13];
  const float* be2 = (const float*)d_in[14];
  float* out = (float*)d_out;

  // ---- workspace layout: peak 170,999,808 B (~163 MiB).
  const size_t NEED = 170999808ULL;
  if (ws_size < NEED) return;
  char* ws = (char*)d_ws;
  u16* xb  = (u16*)(ws + 0L);           // 16,777,216  [M][D]
  u16* Wqt = (u16*)(ws + 16777216L);    //  8,388,608  [H][D][D] (out,in)
  u16* Wkt = (u16*)(ws + 25165824L);    //  8,388,608  (Wqt + H*D*D elems)
  u16* Wvt = (u16*)(ws + 33554432L);    //  8,388,608  (Wqt + 2*H*D*D elems)
  u16* W1t = (u16*)(ws + 41943040L);    //  8,388,608  [D][H*D] ldb=4096
  u16* W2t = (u16*)(ws + 50331648L);    //  2,097,152  [D][D]
  u16* Qh  = (u16*)(ws + 52428800L);    // 16,777,216  [M][D]
  u16* Kh  = (u16*)(ws + 69206016L);    // 16,777,216  (Qh + M*D elems)
  u16* Vt  = (u16*)(ws + 85983232L);    // 16,777,216  [B][D][S] (Qh + 2*M*D elems)
  u16* Sbh = (u16*)(ws + 102760448L);   // 33,554,432  [B][S][S] exp-scores
  u16* Cc2 = (u16*)(ws + 136314880L);   // 33,554,432  [M][2048] per-group concat
  float* biasQKV = (float*)(ws + 169869312L); //    49,152
  float* dpart   = (float*)(ws + 169951232L); // 1,048,576  [B][32][S]
  u16* projb = (u16*)out;               // d_out as bf16 scratch [M][D]; LN2 writes last
  float* y  = (float*)Qh;               // f32 (Qh+Kh dead after head loop)
  u16*   yb = Vt;                       // bf16 (Vt dead)
  float* z2 = (float*)Cc2;              // f32 (Cc2 dead after W1b)

  dim3 blk(256), blk512(512);
  {
    long n4 = (long)M_ * D_ / 4;
    hipLaunchKernelGGL(cvt_f32_bf16, dim3(4096), blk, 0, stream, x, xb, n4);
  }
  hipLaunchKernelGGL(tcvt, dim3(32, 32, H_), blk, 0, stream, Wq, Wqt, D_, D_,
                     (long)D_ * D_, (long)D_ * D_);
  hipLaunchKernelGGL(tcvt, dim3(32, 32, H_), blk, 0, stream, Wk, Wkt, D_, D_,
                     (long)D_ * D_, (long)D_ * D_);
  hipLaunchKernelGGL(tcvt, dim3(32, 32, H_), blk, 0, stream, Wv, Wvt, D_, D_,
                     (long)D_ * D_, (long)D_ * D_);
  hipLaunchKernelGGL(tcvt, dim3(32, 128, 1), blk, 0, stream, W1, W1t, H_ * D_, D_, 0L, 0L);
  hipLaunchKernelGGL(tcvt, dim3(32, 32, 1), blk, 0, stream, W2, W2t, D_, D_, 0L, 0L);
  hipLaunchKernelGGL(biascat, dim3(48), blk, 0, stream, bq, bk, bv, biasQKV);

  for (int g = 0; g < 2; ++g) {
    for (int hh = 0; hh < 2; ++hh) {
      const int h = g * 2 + hh;
      const long wo = (long)h * D_ * D_;
      // Fused QKV: z=0 Q, z=1 K (normal bf16), z=2 V (transposed). 384 blocks,
      // all co-resident (2 blocks/CU x 256 CU); xb A-panels shared across z.
      hipLaunchKernelGGL(kQKV, dim3(4, 32, 3), blk512, 0, stream,
                         xb, Wqt + wo, Qh, biasQKV + (long)h * D_,
                         (const float*)nullptr, (float*)nullptr,
                         D_, 0L, (long)H_ * D_ * D_, (long)M_ * D_);
      hipLaunchKernelGGL(kSC, dim3(8, 8, B_), blk512, 0, stream,
                         Qh, Kh, Sbh, (const float*)nullptr, (const float*)nullptr,
                         dpart, S_, (long)S_ * D_, (long)S_ * D_, (long)S_ * S_);
      // PV: 256x128 4-phase (XCD-swizzled) with in-block dred + normalize
      hipLaunchKernelGGL(kPV, dim3(8, 8, B_), blk512, 0, stream,
                         Sbh, Vt, (void*)(Cc2 + (long)hh * D_), (const float*)nullptr, dpart,
                         S_, S_, S_, 2 * D_,
                         (long)S_ * S_, (long)D_ * S_, (long)S_ * 2 * D_, 1.0f);
    }
    if (g == 0) {
      hipLaunchKernelGGL(kW1a, dim3(8, 32, 1), blk512, 0, stream,
                         Cc2, W1t + (long)g * 2 * D_, (void*)projb, b1, (float*)nullptr,
                         2 * D_, 2 * D_, H_ * D_, D_, 0L, 0L, 0L, 1.0f);
    } else {
      hipLaunchKernelGGL(kW1b, dim3(8, 32, 1), blk512, 0, stream,
                         Cc2, W1t + (long)g * 2 * D_, (void*)projb, (const float*)nullptr,
                         (float*)nullptr, 2 * D_, 2 * D_, H_ * D_, D_, 0L, 0L, 0L, 1.0f);
    }
  }

  // ---- LN1: y = LN(x + projb); also bf16 copy yb
  hipLaunchKernelGGL((ln_kernel<1>), dim3(M_), blk, 0, stream, x, (const void*)projb,
                     g1, be1, y, yb);

  // ---- W2: z2 = yb @ W2t^T + b2 (f32)
  hipLaunchKernelGGL(kW2, dim3(8, 32, 1), blk512, 0, stream,
                     yb, W2t, (void*)z2, b2, (float*)nullptr,
                     D_, D_, D_, D_, 0L, 0L, 0L, 1.0f);

  // ---- LN2: out = LN(y + z2)
  hipLaunchKernelGGL((ln_kernel<0>), dim3(M_), blk, 0, stream, y, (const void*)z2,
                     g2, be2, out, (u16*)nullptr);
}

// Round 22
// 732.415 us; speedup vs baseline: 1.0353x; 1.0353x over previous
//
#include <hip/hip_runtime.h>

using u16 = unsigned short;
using u32 = unsigned int;
typedef __attribute__((ext_vector_type(8))) short s16x8;
typedef __attribute__((ext_vector_type(4))) float f32x4;

typedef uint4   __attribute__((may_alias)) uint4a;
typedef ushort4 __attribute__((may_alias)) ushort4a;
typedef float4  __attribute__((may_alias)) float4a;
typedef u16     __attribute__((may_alias)) u16a;
typedef s16x8   __attribute__((may_alias)) s16x8a;

#define D_ 1024
#define H_ 4
#define B_ 4
#define S_ 2048
#define M_ 8192  /* B_*S_ */

__device__ __forceinline__ float bf2f(u16 u) { return __uint_as_float(((u32)u) << 16); }
__device__ __forceinline__ u16 f2bf(float f) {
  u32 b = __float_as_uint(f);
  return (u16)((b + 0x7fffu + ((b >> 16) & 1u)) >> 16);
}

__device__ __forceinline__ void gload_lds16(const u16* g, u16* l) {
  __builtin_amdgcn_global_load_lds(
      (const __attribute__((address_space(1))) void*)g,
      (__attribute__((address_space(3))) void*)l, 16, 0, 0);
}

#define FENCE asm volatile("" ::: "memory")
#define BAR do { FENCE; __builtin_amdgcn_s_barrier(); FENCE; } while (0)
#define VMC4 asm volatile("s_waitcnt vmcnt(4)" ::: "memory")
#define VMC2 asm volatile("s_waitcnt vmcnt(2)" ::: "memory")

// XCD-bijective swizzle + 4x4 quad decomposition.
// Requires nwg%16==0, (gx*gz)%4==0, gy%4==0 (all grids verified).
__device__ __forceinline__ void swz_decomp(int& x, int& y, int& z) {
  const int gx = gridDim.x, gy = gridDim.y;
  const int nwg = gx * gy * gridDim.z;
  const int flat = (blockIdx.z * gy + blockIdx.y) * gx + blockIdx.x;
  const int swz = (flat & 7) * (nwg >> 3) + (flat >> 3);
  const int t = swz >> 4, i = swz & 15;
  const int tiles_X = (gx * gridDim.z) >> 2;
  const int X = (t % tiles_X) * 4 + (i & 3);
  y = (t / tiles_X) * 4 + (i >> 2);
  z = X / gx;
  x = X % gx;
}

// ---------------- f32 -> bf16 convert ----------------
__global__ __launch_bounds__(256) void cvt_f32_bf16(const float* __restrict__ in,
                                                    u16* __restrict__ out, long n4) {
  long stride = (long)gridDim.x * blockDim.x;
  for (long i = (long)blockIdx.x * blockDim.x + threadIdx.x; i < n4; i += stride) {
    float4 v = ((const float4a*)in)[i];
    ushort4 o;
    o.x = f2bf(v.x); o.y = f2bf(v.y); o.z = f2bf(v.z); o.w = f2bf(v.w);
    ((ushort4a*)out)[i] = o;
  }
}

// ------------- transpose-convert: out[z][n][k] = bf16(in[z][k][n]) -------------
__global__ __launch_bounds__(256) void tcvt(const float* __restrict__ in,
                                            u16* __restrict__ out, int K, int N,
                                            long s_in, long s_out) {
  __shared__ float t[32][33];
  const int z = blockIdx.z;
  in += (long)z * s_in;
  out += (long)z * s_out;
  const int n0 = blockIdx.x * 32, k0 = blockIdx.y * 32;
  const int tx = threadIdx.x & 31, ty = threadIdx.x >> 5;
#pragma unroll
  for (int i = 0; i < 32; i += 8) t[ty + i][tx] = in[(long)(k0 + ty + i) * N + n0 + tx];
  __syncthreads();
#pragma unroll
  for (int i = 0; i < 32; i += 8)
    out[(long)(n0 + ty + i) * K + k0 + tx] = f2bf(t[tx][ty + i]);
}

// ------------- concat biases ----
__global__ __launch_bounds__(256) void biascat(const float* __restrict__ bq,
                                               const float* __restrict__ bk,
                                               const float* __restrict__ bv,
                                               float* __restrict__ o) {
  int i = blockIdx.x * 256 + threadIdx.x;  // grid 48
  float v = (i < 4096) ? bq[i] : ((i < 8192) ? bk[i - 4096] : bv[i - 8192]);
  o[i] = v;
}

// ============ shared MFMA fragment helpers ============
__device__ __forceinline__ s16x8 lds_frag(const u16* buf, int r, int jc) {
  return *(const s16x8a*)&buf[(((r << 3) + (jc ^ (r & 7)))) << 3];
}
__device__ __forceinline__ void readA(const u16* Abuf, int q, int wr, int lane, s16x8 (&afr)[2][2]) {
#pragma unroll
  for (int il = 0; il < 2; ++il)
#pragma unroll
    for (int s = 0; s < 2; ++s)
      afr[il][s] = lds_frag(Abuf, wr * 128 + (q * 2 + il) * 16 + (lane & 15), 4 * s + (lane >> 4));
}

// ============ 256x256 8-phase body (r5-proven) — kQK / kSC, XCD-swizzled ======
__device__ __forceinline__ void readB256(const u16* Bbuf, int wc, int lane, s16x8 (&bfr)[4][2]) {
#pragma unroll
  for (int j = 0; j < 4; ++j)
#pragma unroll
    for (int s = 0; s < 2; ++s)
      bfr[j][s] = lds_frag(Bbuf, wc * 64 + j * 16 + (lane & 15), 4 * s + (lane >> 4));
}
__device__ __forceinline__ void mfma_q256(const s16x8 (&afr)[2][2], const s16x8 (&bfr)[4][2],
                                          f32x4 (&acc)[8][4], int q) {
  __builtin_amdgcn_s_setprio(1);
#pragma unroll
  for (int s = 0; s < 2; ++s)
#pragma unroll
    for (int il = 0; il < 2; ++il)
#pragma unroll
      for (int j = 0; j < 4; ++j)
        acc[q * 2 + il][j] =
            __builtin_amdgcn_mfma_f32_16x16x32_bf16(afr[il][s], bfr[j][s], acc[q * 2 + il][j], 0, 0, 0);
  __builtin_amdgcn_s_setprio(0);
}

template <int MODE>
__device__ __forceinline__ void g256_body(
    const u16* __restrict__ A, const u16* __restrict__ Bm, u16* __restrict__ Cp,
    const float* __restrict__ bias, const float* __restrict__ bias2,
    float* __restrict__ dpart, int ldc, long sA, long sB, long sC) {
  __shared__ u16 Al[2][16384];
  __shared__ u16 Bl[2][16384];
  int bx, by, z;
  swz_decomp(bx, by, z);  // XCD-bijective block mapping
  A += (long)z * sA;
  Bm += (long)z * sB;
  const long coff = (long)z * sC;
  const int bm = by * 256, bn = bx * 256;
  const int tid = threadIdx.x;
  const int lane = tid & 63;
  const int w = tid >> 6;
  const int wr = w >> 2, wc = w & 3;
  f32x4 acc[8][4] = {};
  const int nt2 = D_ >> 7;

  auto stage = [&](const u16* src, int b0, u16* lbuf, int h, int kt) {
    const int k0 = kt << 6;
#pragma unroll
    for (int it = 0; it < 2; ++it) {
      int c = w * 128 + it * 64 + lane;
      int row = h * 128 + (c >> 3);
      int j = (c & 7) ^ (row & 7);
      gload_lds16(src + (long)(b0 + row) * D_ + (k0 + j * 8),
                  lbuf + ((h * 1024 + w * 128 + it * 64) << 3));
    }
  };

  stage(A, bm, Al[0], 0, 0);
  stage(A, bm, Al[0], 1, 0);
  stage(Bm, bn, Bl[0], 0, 0);
  stage(Bm, bn, Bl[0], 1, 0);
  stage(Bm, bn, Bl[1], 0, 1);
  stage(Bm, bn, Bl[1], 1, 1);
  VMC4;
  BAR;

  s16x8 bfr[4][2];
  for (int i2 = 0; i2 < nt2; ++i2) {
    const int t = i2 * 2;
    s16x8 afr[2][2];
    readB256(Bl[0], wc, lane, bfr);
    readA(Al[0], 0, wr, lane, afr);
    stage(A, bm, Al[1], 0, t + 1);
    BAR;
    mfma_q256(afr, bfr, acc, 0);
    BAR;
    readA(Al[0], 1, wr, lane, afr);
    stage(A, bm, Al[1], 1, t + 1);
    BAR;
    mfma_q256(afr, bfr, acc, 1);
    BAR;
    readA(Al[0], 2, wr, lane, afr);
    stage(Bm, bn, Bl[0], 0, t + 2);
    BAR;
    mfma_q256(afr, bfr, acc, 2);
    BAR;
    readA(Al[0], 3, wr, lane, afr);
    stage(Bm, bn, Bl[0], 1, t + 2);
    BAR;
    mfma_q256(afr, bfr, acc, 3);
    VMC4;
    BAR;
    readB256(Bl[1], wc, lane, bfr);
    readA(Al[1], 0, wr, lane, afr);
    stage(A, bm, Al[0], 0, t + 2);
    BAR;
    mfma_q256(afr, bfr, acc, 0);
    BAR;
    readA(Al[1], 1, wr, lane, afr);
    stage(A, bm, Al[0], 1, t + 2);
    BAR;
    mfma_q256(afr, bfr, acc, 1);
    BAR;
    readA(Al[1], 2, wr, lane, afr);
    stage(Bm, bn, Bl[1], 0, t + 3);
    BAR;
    mfma_q256(afr, bfr, acc, 2);
    BAR;
    readA(Al[1], 3, wr, lane, afr);
    stage(Bm, bn, Bl[1], 1, t + 3);
    BAR;
    mfma_q256(afr, bfr, acc, 3);
    VMC4;
    BAR;
  }

  if (MODE == 0) {
    const float* bb = (z == 1) ? bias2 : bias;
#pragma unroll
    for (int i = 0; i < 8; i++) {
      int mbase = bm + wr * 128 + i * 16 + ((lane >> 4) << 2);
#pragma unroll
      for (int j = 0; j < 4; j++) {
        int n = bn + wc * 64 + j * 16 + (lane & 15);
        float bv = bb[n];
#pragma unroll
        for (int r = 0; r < 4; r++)
          ((u16a*)Cp)[coff + (long)(mbase + r) * ldc + n] = f2bf(acc[i][j][r] + bv);
      }
    }
  } else {
#pragma unroll
    for (int i = 0; i < 8; i++) {
      int mbase = bm + wr * 128 + i * 16 + ((lane >> 4) << 2);
#pragma unroll
      for (int r = 0; r < 4; r++) {
        const int mm = mbase + r;
        float rowsum = 0.f;
#pragma unroll
        for (int j = 0; j < 4; j++) {
          int n = bn + wc * 64 + j * 16 + (lane & 15);
          float e = __expf(acc[i][j][r] * 0.03125f);
          ((u16a*)Cp)[coff + (long)mm * ldc + n] = f2bf(e);
          rowsum += e;
        }
        rowsum += __shfl_xor(rowsum, 1, 64);
        rowsum += __shfl_xor(rowsum, 2, 64);
        rowsum += __shfl_xor(rowsum, 4, 64);
        rowsum += __shfl_xor(rowsum, 8, 64);
        if ((lane & 15) == 0)
          dpart[((long)z * 32 + (bx * 4 + wc)) * S_ + mm] = rowsum;
      }
    }
  }
}

__global__ __launch_bounds__(512, 2) void kQK(
    const u16* __restrict__ A, const u16* __restrict__ Bm, u16* __restrict__ Cp,
    const float* __restrict__ bias, const float* __restrict__ bias2,
    float* __restrict__ dpart, int ldc, long sA, long sB, long sC) {
  g256_body<0>(A, Bm, Cp, bias, bias2, dpart, ldc, sA, sB, sC);
}
__global__ __launch_bounds__(512, 2) void kSC(
    const u16* __restrict__ A, const u16* __restrict__ Bm, u16* __restrict__ Cp,
    const float* __restrict__ bias, const float* __restrict__ bias2,
    float* __restrict__ dpart, int ldc, long sA, long sB, long sC) {
  g256_body<1>(A, Bm, Cp, bias, bias2, dpart, ldc, sA, sB, sC);
}

// ============ 256x128 4-phase body — kV / kPV / kW1a / kW1b / kW2 ============
// 16 MFMA per barrier pair; XCD-swizzled. Stage plan per K-tile pair:
// P1: A(t+1)x2; P2: B(t+2) +VMC2; P3: A(t+2)x2; P4: B(t+3) +VMC2.
// OUT_MODE: 0 f32+bias, 1 bf16+bias, 2 bf16 V-transpose+bias,
//           5 PV-normalize (sinv from dpart), 6 bf16 RMW.
__device__ __forceinline__ void readB128(const u16* Bbuf, int wc, int lane, s16x8 (&bfr)[2][2]) {
#pragma unroll
  for (int j = 0; j < 2; ++j)
#pragma unroll
    for (int s = 0; s < 2; ++s)
      bfr[j][s] = lds_frag(Bbuf, wc * 32 + j * 16 + (lane & 15), 4 * s + (lane >> 4));
}
__device__ __forceinline__ void mfma_q128(const s16x8 (&afr)[2][2], const s16x8 (&bfr)[2][2],
                                          f32x4 (&acc)[8][2], int q) {
#pragma unroll
  for (int s = 0; s < 2; ++s)
#pragma unroll
    for (int il = 0; il < 2; ++il)
#pragma unroll
      for (int j = 0; j < 2; ++j)
        acc[q * 2 + il][j] =
            __builtin_amdgcn_mfma_f32_16x16x32_bf16(afr[il][s], bfr[j][s], acc[q * 2 + il][j], 0, 0, 0);
}

template <int OUT_MODE, int HAS_BIAS>
__device__ __forceinline__ void g256n_body(
    const u16* __restrict__ A, const u16* __restrict__ Bm, void* __restrict__ Cp,
    const float* __restrict__ bias, float* __restrict__ dpart,
    int K, int lda, int ldb, int ldc, long sA, long sB, long sC, float scale) {
  __shared__ u16 Al[2][16384];  // 2 x 32 KB: 256 rows x 64 k
  __shared__ u16 Bl[2][8192];   // 2 x 16 KB: 128 rows x 64 k
  __shared__ float sinv[256];
  int bx, by, z;
  swz_decomp(bx, by, z);
  A += (long)z * sA;
  Bm += (long)z * sB;
  const long coff = (long)z * sC;
  const int bm = by * 256, bn = bx * 128;
  const int tid = threadIdx.x;
  const int lane = tid & 63;
  const int w = tid >> 6;
  const int wr = w >> 2, wc = w & 3;  // per-wave 128 rows x 32 cols
  f32x4 acc[8][2] = {};
  const int nt2 = K >> 7;

  auto stageA = [&](u16* Abuf, int h, int kt) {
    const int k0 = kt << 6;
#pragma unroll
    for (int it = 0; it < 2; ++it) {
      int c = w * 128 + it * 64 + lane;
      int row = h * 128 + (c >> 3);
      int j = (c & 7) ^ (row & 7);
      gload_lds16(A + (long)(bm + row) * lda + (k0 + j * 8),
                  Abuf + ((h * 1024 + w * 128 + it * 64) << 3));
    }
  };
  auto stageB = [&](u16* Bbuf, int kt) {
    const int k0 = kt << 6;
#pragma unroll
    for (int it = 0; it < 2; ++it) {
      int c = w * 128 + it * 64 + lane;
      int row = c >> 3;
      int j = (c & 7) ^ (row & 7);
      gload_lds16(Bm + (long)(bn + row) * ldb + (k0 + j * 8),
                  Bbuf + ((w * 128 + it * 64) << 3));
    }
  };

  // prologue: A0<-t0 (2 calls), B0<-t0, B1<-t1; VMC2 leaves B1 in flight
  stageA(Al[0], 0, 0);
  stageA(Al[0], 1, 0);
  stageB(Bl[0], 0);
  stageB(Bl[1], 1);
  VMC2;
  BAR;

  s16x8 bfr[2][2];
  for (int i2 = 0; i2 < nt2; ++i2) {
    const int t = i2 * 2;
    s16x8 afrA[2][2], afrB[2][2];
    // P1: tile t quads 0,1 from buf0; stage A(t+1)
    readB128(Bl[0], wc, lane, bfr);
    readA(Al[0], 0, wr, lane, afrA);
    readA(Al[0], 1, wr, lane, afrB);
    stageA(Al[1], 0, t + 1);
    stageA(Al[1], 1, t + 1);
    BAR;
    __builtin_amdgcn_s_setprio(1);
    mfma_q128(afrA, bfr, acc, 0);
    mfma_q128(afrB, bfr, acc, 1);
    __builtin_amdgcn_s_setprio(0);
    BAR;
    // P2: tile t quads 2,3; stage B(t+2)
    readA(Al[0], 2, wr, lane, afrA);
    readA(Al[0], 3, wr, lane, afrB);
    stageB(Bl[0], t + 2);
    BAR;
    __builtin_amdgcn_s_setprio(1);
    mfma_q128(afrA, bfr, acc, 2);
    mfma_q128(afrB, bfr, acc, 3);
    __builtin_amdgcn_s_setprio(0);
    VMC2;  // leave B0(t+2) in flight
    BAR;
    // P3: tile t+1 quads 0,1 from buf1; stage A(t+2)
    readB128(Bl[1], wc, lane, bfr);
    readA(Al[1], 0, wr, lane, afrA);
    readA(Al[1], 1, wr, lane, afrB);
    stageA(Al[0], 0, t + 2);
    stageA(Al[0], 1, t + 2);
    BAR;
    __builtin_amdgcn_s_setprio(1);
    mfma_q128(afrA, bfr, acc, 0);
    mfma_q128(afrB, bfr, acc, 1);
    __builtin_amdgcn_s_setprio(0);
    BAR;
    // P4: tile t+1 quads 2,3; stage B(t+3)
    readA(Al[1], 2, wr, lane, afrA);
    readA(Al[1], 3, wr, lane, afrB);
    stageB(Bl[1], t + 3);
    BAR;
    __builtin_amdgcn_s_setprio(1);
    mfma_q128(afrA, bfr, acc, 2);
    mfma_q128(afrB, bfr, acc, 3);
    __builtin_amdgcn_s_setprio(0);
    VMC2;  // leave B1(t+3) in flight
    BAR;
  }

  if (OUT_MODE == 5) {
    if (tid < 256) {
      const int row = bm + tid;
      float s = 0.f;
#pragma unroll
      for (int p = 0; p < 32; ++p) s += dpart[((long)z * 32 + p) * S_ + row];
      sinv[tid] = 1.0f / s;
    }
    __syncthreads();
#pragma unroll
    for (int i = 0; i < 8; i++) {
      int mloc = wr * 128 + i * 16 + ((lane >> 4) << 2);
      float inv[4];
#pragma unroll
      for (int r = 0; r < 4; r++) inv[r] = sinv[mloc + r];
#pragma unroll
      for (int j = 0; j < 2; j++) {
        int n = bn + wc * 32 + j * 16 + (lane & 15);
#pragma unroll
        for (int r = 0; r < 4; r++) {
          ((u16a*)Cp)[coff + (long)(bm + mloc + r) * ldc + n] = f2bf(acc[i][j][r] * inv[r]);
        }
      }
    }
    return;
  }
#pragma unroll
  for (int i = 0; i < 8; i++) {
    int mbase = bm + wr * 128 + i * 16 + ((lane >> 4) << 2);
#pragma unroll
    for (int j = 0; j < 2; j++) {
      int n = bn + wc * 32 + j * 16 + (lane & 15);
      float bv = 0.f;
      if (HAS_BIAS) bv = bias[n];
      if (OUT_MODE == 2) {
        ushort4 o;
        o.x = f2bf(acc[i][j][0] * scale + bv);
        o.y = f2bf(acc[i][j][1] * scale + bv);
        o.z = f2bf(acc[i][j][2] * scale + bv);
        o.w = f2bf(acc[i][j][3] * scale + bv);
        long idx = coff + (long)(mbase >> 11) * ((long)D_ * S_) + (long)n * S_ + (mbase & 2047);
        *(ushort4a*)&((u16a*)Cp)[idx] = o;
      } else {
#pragma unroll
        for (int r = 0; r < 4; r++) {
          float v = acc[i][j][r] * scale + bv;
          long idx = coff + (long)(mbase + r) * ldc + n;
          if (OUT_MODE == 1) {
            ((u16a*)Cp)[idx] = f2bf(v);
          } else if (OUT_MODE == 6) {
            u16a* Cb = (u16a*)Cp;
            Cb[idx] = f2bf(bf2f(Cb[idx]) + v);
          } else {
            ((float*)Cp)[idx] = v;
          }
        }
      }
    }
  }
}

#define G256N_ARGS \
    const u16* __restrict__ A, const u16* __restrict__ Bm, void* __restrict__ Cp, \
    const float* __restrict__ bias, float* __restrict__ dpart, \
    int K, int lda, int ldb, int ldc, long sA, long sB, long sC, float scale
#define G256N_FWD A, Bm, Cp, bias, dpart, K, lda, ldb, ldc, sA, sB, sC, scale

__global__ __launch_bounds__(512, 2) void kV(G256N_ARGS)   { g256n_body<2, 1>(G256N_FWD); }
__global__ __launch_bounds__(512, 2) void kPV(G256N_ARGS)  { g256n_body<5, 0>(G256N_FWD); }
__global__ __launch_bounds__(512, 2) void kW1a(G256N_ARGS) { g256n_body<1, 1>(G256N_FWD); }
__global__ __launch_bounds__(512, 2) void kW1b(G256N_ARGS) { g256n_body<6, 0>(G256N_FWD); }
__global__ __launch_bounds__(512, 2) void kW2(G256N_ARGS)  { g256n_body<1, 1>(G256N_FWD); }

// ---------------- LayerNorm over 1024; RBF: residual in bf16 ----------------
template <int RBF>
__global__ __launch_bounds__(256) void ln_kernel(
    const float* __restrict__ X, const void* __restrict__ R,
    const float* __restrict__ g, const float* __restrict__ be,
    float* __restrict__ Y, u16* __restrict__ Yb) {
  const long row = blockIdx.x;
  const int t = threadIdx.x, lane = t & 63, w = t >> 6;
  const long base = row * 1024 + t * 4;
  float4 a = *(const float4a*)(X + base);
  float r0, r1, r2, r3;
  if (RBF) {
    ushort4 rb = *(const ushort4a*)((const u16*)R + base);
    r0 = bf2f(rb.x); r1 = bf2f(rb.y); r2 = bf2f(rb.z); r3 = bf2f(rb.w);
  } else {
    float4 b = *(const float4a*)((const float*)R + base);
    r0 = b.x; r1 = b.y; r2 = b.z; r3 = b.w;
  }
  float v0 = a.x + r0, v1 = a.y + r1, v2 = a.z + r2, v3 = a.w + r3;
  float s = v0 + v1 + v2 + v3;
  float q = v0 * v0 + v1 * v1 + v2 * v2 + v3 * v3;
#pragma unroll
  for (int o = 32; o > 0; o >>= 1) { s += __shfl_xor(s, o, 64); q += __shfl_xor(q, o, 64); }
  __shared__ float rs[4], rq[4];
  if (lane == 0) { rs[w] = s; rq[w] = q; }
  __syncthreads();
  s = rs[0] + rs[1] + rs[2] + rs[3];
  q = rq[0] + rq[1] + rq[2] + rq[3];
  const float mu = s * (1.f / 1024.f);
  const float var = q * (1.f / 1024.f) - mu * mu;
  const float rstd = rsqrtf(var + 1e-5f);
  float4 gv = *(const float4a*)(g + t * 4);
  float4 bv = *(const float4a*)(be + t * 4);
  float o0 = (v0 - mu) * rstd * gv.x + bv.x;
  float o1 = (v1 - mu) * rstd * gv.y + bv.y;
  float o2 = (v2 - mu) * rstd * gv.z + bv.z;
  float o3 = (v3 - mu) * rstd * gv.w + bv.w;
  float4 o4; o4.x = o0; o4.y = o1; o4.z = o2; o4.w = o3;
  *(float4a*)(Y + base) = o4;
  if (Yb) {
    ushort4 ob; ob.x = f2bf(o0); ob.y = f2bf(o1); ob.z = f2bf(o2); ob.w = f2bf(o3);
    *(ushort4a*)(Yb + base) = ob;
  }
}

extern "C" void kernel_launch(void* const* d_in, const int* in_sizes, int n_in,
                              void* d_out, int out_size, void* d_ws, size_t ws_size,
                              hipStream_t stream) {
  const float* x   = (const float*)d_in[0];
  const float* Wq  = (const float*)d_in[1];
  const float* bq  = (const float*)d_in[2];
  const float* Wk  = (const float*)d_in[3];
  const float* bk  = (const float*)d_in[4];
  const float* Wv  = (const float*)d_in[5];
  const float* bv  = (const float*)d_in[6];
  const float* W1  = (const float*)d_in[7];
  const float* b1  = (const float*)d_in[8];
  const float* g1  = (const float*)d_in[9];
  const float* be1 = (const float*)d_in[10];
  const float* W2  = (const float*)d_in[11];
  const float* b2  = (const float*)d_in[12];
  const float* g2  = (const float*)d_in[13];
  const float* be2 = (const float*)d_in[14];
  float* out = (float*)d_out;

  // ---- workspace layout: peak 170,999,808 B (~163 MiB).
  const size_t NEED = 170999808ULL;
  if (ws_size < NEED) return;
  char* ws = (char*)d_ws;
  u16* xb  = (u16*)(ws + 0L);           // 16,777,216  [M][D]
  u16* Wqt = (u16*)(ws + 16777216L);    //  8,388,608  [H][D][D] (out,in)
  u16* Wkt = (u16*)(ws + 25165824L);    //  8,388,608
  u16* Wvt = (u16*)(ws + 33554432L);    //  8,388,608
  u16* W1t = (u16*)(ws + 41943040L);    //  8,388,608  [D][H*D] ldb=4096
  u16* W2t = (u16*)(ws + 50331648L);    //  2,097,152  [D][D]
  u16* Qh  = (u16*)(ws + 52428800L);    // 16,777,216  [M][D]
  u16* Kh  = (u16*)(ws + 69206016L);    // 16,777,216  (contiguous after Qh)
  u16* Vt  = (u16*)(ws + 85983232L);    // 16,777,216  [B][D][S]
  u16* Sbh = (u16*)(ws + 102760448L);   // 33,554,432  [B][S][S] exp-scores
  u16* Cc2 = (u16*)(ws + 136314880L);   // 33,554,432  [M][2048] per-group concat
  float* biasQKV = (float*)(ws + 169869312L); //    49,152
  float* dpart   = (float*)(ws + 169951232L); // 1,048,576  [B][32][S]
  u16* projb = (u16*)out;               // d_out as bf16 scratch [M][D]; LN2 writes last
  float* y  = (float*)Qh;               // f32 (Qh+Kh dead after head loop)
  u16*   yb = Vt;                       // bf16 (Vt dead)
  u16* z2b16 = Cc2;                     // bf16 W2 output (Cc2 dead after W1b)

  dim3 blk(256), blk512(512);
  {
    long n4 = (long)M_ * D_ / 4;
    hipLaunchKernelGGL(cvt_f32_bf16, dim3(4096), blk, 0, stream, x, xb, n4);
  }
  hipLaunchKernelGGL(tcvt, dim3(32, 32, H_), blk, 0, stream, Wq, Wqt, D_, D_,
                     (long)D_ * D_, (long)D_ * D_);
  hipLaunchKernelGGL(tcvt, dim3(32, 32, H_), blk, 0, stream, Wk, Wkt, D_, D_,
                     (long)D_ * D_, (long)D_ * D_);
  hipLaunchKernelGGL(tcvt, dim3(32, 32, H_), blk, 0, stream, Wv, Wvt, D_, D_,
                     (long)D_ * D_, (long)D_ * D_);
  hipLaunchKernelGGL(tcvt, dim3(32, 128, 1), blk, 0, stream, W1, W1t, H_ * D_, D_, 0L, 0L);
  hipLaunchKernelGGL(tcvt, dim3(32, 32, 1), blk, 0, stream, W2, W2t, D_, D_, 0L, 0L);
  hipLaunchKernelGGL(biascat, dim3(48), blk, 0, stream, bq, bk, bv, biasQKV);

  for (int g = 0; g < 2; ++g) {
    for (int hh = 0; hh < 2; ++hh) {
      const int h = g * 2 + hh;
      const long wo = (long)h * D_ * D_;
      hipLaunchKernelGGL(kQK, dim3(4, 32, 2), blk512, 0, stream,
                         xb, Wqt + wo, Qh, biasQKV + (long)h * D_,
                         biasQKV + 4096 + (long)h * D_, (float*)nullptr,
                         D_, 0L, (long)H_ * D_ * D_, (long)M_ * D_);
      // V: 256x128 4-phase (XCD-swizzled), transposed output [B][D][S]
      hipLaunchKernelGGL(kV, dim3(8, 32, 1), blk512, 0, stream,
                         xb, Wvt + wo, (void*)Vt, biasQKV + 8192 + (long)h * D_,
                         (float*)nullptr, D_, D_, D_, D_, 0L, 0L, 0L, 1.0f);
      hipLaunchKernelGGL(kSC, dim3(8, 8, B_), blk512, 0, stream,
                         Qh, Kh, Sbh, (const float*)nullptr, (const float*)nullptr,
                         dpart, S_, (long)S_ * D_, (long)S_ * D_, (long)S_ * S_);
      // PV: 256x128 4-phase (XCD-swizzled) with in-block dred + normalize
      hipLaunchKernelGGL(kPV, dim3(8, 8, B_), blk512, 0, stream,
                         Sbh, Vt, (void*)(Cc2 + (long)hh * D_), (const float*)nullptr, dpart,
                         S_, S_, S_, 2 * D_,
                         (long)S_ * S_, (long)D_ * S_, (long)S_ * 2 * D_, 1.0f);
    }
    if (g == 0) {
      hipLaunchKernelGGL(kW1a, dim3(8, 32, 1), blk512, 0, stream,
                         Cc2, W1t + (long)g * 2 * D_, (void*)projb, b1, (float*)nullptr,
                         2 * D_, 2 * D_, H_ * D_, D_, 0L, 0L, 0L, 1.0f);
    } else {
      hipLaunchKernelGGL(kW1b, dim3(8, 32, 1), blk512, 0, stream,
                         Cc2, W1t + (long)g * 2 * D_, (void*)projb, (const float*)nullptr,
                         (float*)nullptr, 2 * D_, 2 * D_, H_ * D_, D_, 0L, 0L, 0L, 1.0f);
    }
  }

  // ---- LN1: y = LN(x + projb); also bf16 copy yb
  hipLaunchKernelGGL((ln_kernel<1>), dim3(M_), blk, 0, stream, x, (const void*)projb,
                     g1, be1, y, yb);

  // ---- W2: z2b16 = bf16(yb @ W2t^T + b2)
  hipLaunchKernelGGL(kW2, dim3(8, 32, 1), blk512, 0, stream,
                     yb, W2t, (void*)z2b16, b2, (float*)nullptr,
                     D_, D_, D_, D_, 0L, 0L, 0L, 1.0f);

  // ---- LN2: out = LN(y + z2b16)   (bf16 residual)
  hipLaunchKernelGGL((ln_kernel<1>), dim3(M_), blk, 0, stream, y, (const void*)z2b16,
                     g2, be2, out, (u16*)nullptr);
}

// Round 23
// 727.103 us; speedup vs baseline: 1.0428x; 1.0073x over previous
//
#include <hip/hip_runtime.h>

using u16 = unsigned short;
using u32 = unsigned int;
typedef __attribute__((ext_vector_type(8))) short s16x8;
typedef __attribute__((ext_vector_type(4))) float f32x4;

typedef uint4   __attribute__((may_alias)) uint4a;
typedef ushort4 __attribute__((may_alias)) ushort4a;
typedef float4  __attribute__((may_alias)) float4a;
typedef u16     __attribute__((may_alias)) u16a;
typedef s16x8   __attribute__((may_alias)) s16x8a;

#define D_ 1024
#define H_ 4
#define B_ 4
#define S_ 2048
#define M_ 8192  /* B_*S_ */

__device__ __forceinline__ float bf2f(u16 u) { return __uint_as_float(((u32)u) << 16); }
__device__ __forceinline__ u16 f2bf(float f) {
  u32 b = __float_as_uint(f);
  return (u16)((b + 0x7fffu + ((b >> 16) & 1u)) >> 16);
}

__device__ __forceinline__ void gload_lds16(const u16* g, u16* l) {
  __builtin_amdgcn_global_load_lds(
      (const __attribute__((address_space(1))) void*)g,
      (__attribute__((address_space(3))) void*)l, 16, 0, 0);
}

#define FENCE asm volatile("" ::: "memory")
#define BAR do { FENCE; __builtin_amdgcn_s_barrier(); FENCE; } while (0)
#define VMC4 asm volatile("s_waitcnt vmcnt(4)" ::: "memory")
#define VMC2 asm volatile("s_waitcnt vmcnt(2)" ::: "memory")

// XCD-bijective swizzle + 4x4 quad decomposition.
// Requires nwg%16==0, (gx*gz)%4==0, gy%4==0 (all grids verified).
__device__ __forceinline__ void swz_decomp(int& x, int& y, int& z) {
  const int gx = gridDim.x, gy = gridDim.y;
  const int nwg = gx * gy * gridDim.z;
  const int flat = (blockIdx.z * gy + blockIdx.y) * gx + blockIdx.x;
  const int swz = (flat & 7) * (nwg >> 3) + (flat >> 3);
  const int t = swz >> 4, i = swz & 15;
  const int tiles_X = (gx * gridDim.z) >> 2;
  const int X = (t % tiles_X) * 4 + (i & 3);
  y = (t / tiles_X) * 4 + (i >> 2);
  z = X / gx;
  x = X % gx;
}

// ---------------- f32 -> bf16 convert ----------------
__global__ __launch_bounds__(256) void cvt_f32_bf16(const float* __restrict__ in,
                                                    u16* __restrict__ out, long n4) {
  long stride = (long)gridDim.x * blockDim.x;
  for (long i = (long)blockIdx.x * blockDim.x + threadIdx.x; i < n4; i += stride) {
    float4 v = ((const float4a*)in)[i];
    ushort4 o;
    o.x = f2bf(v.x); o.y = f2bf(v.y); o.z = f2bf(v.z); o.w = f2bf(v.w);
    ((ushort4a*)out)[i] = o;
  }
}

// ------------- transpose-convert: out[z][n][k] = bf16(in[z][k][n]) -------------
__global__ __launch_bounds__(256) void tcvt(const float* __restrict__ in,
                                            u16* __restrict__ out, int K, int N,
                                            long s_in, long s_out) {
  __shared__ float t[32][33];
  const int z = blockIdx.z;
  in += (long)z * s_in;
  out += (long)z * s_out;
  const int n0 = blockIdx.x * 32, k0 = blockIdx.y * 32;
  const int tx = threadIdx.x & 31, ty = threadIdx.x >> 5;
#pragma unroll
  for (int i = 0; i < 32; i += 8) t[ty + i][tx] = in[(long)(k0 + ty + i) * N + n0 + tx];
  __syncthreads();
#pragma unroll
  for (int i = 0; i < 32; i += 8)
    out[(long)(n0 + ty + i) * K + k0 + tx] = f2bf(t[tx][ty + i]);
}

// ------------- concat biases ----
__global__ __launch_bounds__(256) void biascat(const float* __restrict__ bq,
                                               const float* __restrict__ bk,
                                               const float* __restrict__ bv,
                                               float* __restrict__ o) {
  int i = blockIdx.x * 256 + threadIdx.x;  // grid 48
  float v = (i < 4096) ? bq[i] : ((i < 8192) ? bk[i - 4096] : bv[i - 8192]);
  o[i] = v;
}

// ============ shared MFMA fragment helpers ============
__device__ __forceinline__ s16x8 lds_frag(const u16* buf, int r, int jc) {
  return *(const s16x8a*)&buf[(((r << 3) + (jc ^ (r & 7)))) << 3];
}
__device__ __forceinline__ void readA(const u16* Abuf, int q, int wr, int lane, s16x8 (&afr)[2][2]) {
#pragma unroll
  for (int il = 0; il < 2; ++il)
#pragma unroll
    for (int s = 0; s < 2; ++s)
      afr[il][s] = lds_frag(Abuf, wr * 128 + (q * 2 + il) * 16 + (lane & 15), 4 * s + (lane >> 4));
}

// ============ 256x256 8-phase body (r5-proven) — kQK / kSC, XCD-swizzled ======
__device__ __forceinline__ void readB256(const u16* Bbuf, int wc, int lane, s16x8 (&bfr)[4][2]) {
#pragma unroll
  for (int j = 0; j < 4; ++j)
#pragma unroll
    for (int s = 0; s < 2; ++s)
      bfr[j][s] = lds_frag(Bbuf, wc * 64 + j * 16 + (lane & 15), 4 * s + (lane >> 4));
}
__device__ __forceinline__ void mfma_q256(const s16x8 (&afr)[2][2], const s16x8 (&bfr)[4][2],
                                          f32x4 (&acc)[8][4], int q) {
  __builtin_amdgcn_s_setprio(1);
#pragma unroll
  for (int s = 0; s < 2; ++s)
#pragma unroll
    for (int il = 0; il < 2; ++il)
#pragma unroll
      for (int j = 0; j < 4; ++j)
        acc[q * 2 + il][j] =
            __builtin_amdgcn_mfma_f32_16x16x32_bf16(afr[il][s], bfr[j][s], acc[q * 2 + il][j], 0, 0, 0);
  __builtin_amdgcn_s_setprio(0);
}

template <int MODE>
__device__ __forceinline__ void g256_body(
    const u16* __restrict__ A, const u16* __restrict__ Bm, u16* __restrict__ Cp,
    const float* __restrict__ bias, const float* __restrict__ bias2,
    float* __restrict__ dpart, int ldc, long sA, long sB, long sC) {
  __shared__ u16 Al[2][16384];
  __shared__ u16 Bl[2][16384];
  int bx, by, z;
  swz_decomp(bx, by, z);  // XCD-bijective block mapping
  A += (long)z * sA;
  Bm += (long)z * sB;
  const long coff = (long)z * sC;
  const int bm = by * 256, bn = bx * 256;
  const int tid = threadIdx.x;
  const int lane = tid & 63;
  const int w = tid >> 6;
  const int wr = w >> 2, wc = w & 3;
  f32x4 acc[8][4] = {};
  const int nt2 = D_ >> 7;

  auto stage = [&](const u16* src, int b0, u16* lbuf, int h, int kt) {
    const int k0 = kt << 6;
#pragma unroll
    for (int it = 0; it < 2; ++it) {
      int c = w * 128 + it * 64 + lane;
      int row = h * 128 + (c >> 3);
      int j = (c & 7) ^ (row & 7);
      gload_lds16(src + (long)(b0 + row) * D_ + (k0 + j * 8),
                  lbuf + ((h * 1024 + w * 128 + it * 64) << 3));
    }
  };

  stage(A, bm, Al[0], 0, 0);
  stage(A, bm, Al[0], 1, 0);
  stage(Bm, bn, Bl[0], 0, 0);
  stage(Bm, bn, Bl[0], 1, 0);
  stage(Bm, bn, Bl[1], 0, 1);
  stage(Bm, bn, Bl[1], 1, 1);
  VMC4;
  BAR;

  s16x8 bfr[4][2];
  for (int i2 = 0; i2 < nt2; ++i2) {
    const int t = i2 * 2;
    s16x8 afr[2][2];
    readB256(Bl[0], wc, lane, bfr);
    readA(Al[0], 0, wr, lane, afr);
    stage(A, bm, Al[1], 0, t + 1);
    BAR;
    mfma_q256(afr, bfr, acc, 0);
    BAR;
    readA(Al[0], 1, wr, lane, afr);
    stage(A, bm, Al[1], 1, t + 1);
    BAR;
    mfma_q256(afr, bfr, acc, 1);
    BAR;
    readA(Al[0], 2, wr, lane, afr);
    stage(Bm, bn, Bl[0], 0, t + 2);
    BAR;
    mfma_q256(afr, bfr, acc, 2);
    BAR;
    readA(Al[0], 3, wr, lane, afr);
    stage(Bm, bn, Bl[0], 1, t + 2);
    BAR;
    mfma_q256(afr, bfr, acc, 3);
    VMC4;
    BAR;
    readB256(Bl[1], wc, lane, bfr);
    readA(Al[1], 0, wr, lane, afr);
    stage(A, bm, Al[0], 0, t + 2);
    BAR;
    mfma_q256(afr, bfr, acc, 0);
    BAR;
    readA(Al[1], 1, wr, lane, afr);
    stage(A, bm, Al[0], 1, t + 2);
    BAR;
    mfma_q256(afr, bfr, acc, 1);
    BAR;
    readA(Al[1], 2, wr, lane, afr);
    stage(Bm, bn, Bl[1], 0, t + 3);
    BAR;
    mfma_q256(afr, bfr, acc, 2);
    BAR;
    readA(Al[1], 3, wr, lane, afr);
    stage(Bm, bn, Bl[1], 1, t + 3);
    BAR;
    mfma_q256(afr, bfr, acc, 3);
    VMC4;
    BAR;
  }

  if (MODE == 0) {
    const float* bb = (z == 1) ? bias2 : bias;
#pragma unroll
    for (int i = 0; i < 8; i++) {
      int mbase = bm + wr * 128 + i * 16 + ((lane >> 4) << 2);
#pragma unroll
      for (int j = 0; j < 4; j++) {
        int n = bn + wc * 64 + j * 16 + (lane & 15);
        float bv = bb[n];
#pragma unroll
        for (int r = 0; r < 4; r++)
          ((u16a*)Cp)[coff + (long)(mbase + r) * ldc + n] = f2bf(acc[i][j][r] + bv);
      }
    }
  } else {
#pragma unroll
    for (int i = 0; i < 8; i++) {
      int mbase = bm + wr * 128 + i * 16 + ((lane >> 4) << 2);
#pragma unroll
      for (int r = 0; r < 4; r++) {
        const int mm = mbase + r;
        float rowsum = 0.f;
#pragma unroll
        for (int j = 0; j < 4; j++) {
          int n = bn + wc * 64 + j * 16 + (lane & 15);
          float e = __expf(acc[i][j][r] * 0.03125f);
          ((u16a*)Cp)[coff + (long)mm * ldc + n] = f2bf(e);
          rowsum += e;
        }
        rowsum += __shfl_xor(rowsum, 1, 64);
        rowsum += __shfl_xor(rowsum, 2, 64);
        rowsum += __shfl_xor(rowsum, 4, 64);
        rowsum += __shfl_xor(rowsum, 8, 64);
        if ((lane & 15) == 0)
          dpart[((long)z * 32 + (bx * 4 + wc)) * S_ + mm] = rowsum;
      }
    }
  }
}

__global__ __launch_bounds__(512, 2) void kQK(
    const u16* __restrict__ A, const u16* __restrict__ Bm, u16* __restrict__ Cp,
    const float* __restrict__ bias, const float* __restrict__ bias2,
    float* __restrict__ dpart, int ldc, long sA, long sB, long sC) {
  g256_body<0>(A, Bm, Cp, bias, bias2, dpart, ldc, sA, sB, sC);
}
__global__ __launch_bounds__(512, 2) void kSC(
    const u16* __restrict__ A, const u16* __restrict__ Bm, u16* __restrict__ Cp,
    const float* __restrict__ bias, const float* __restrict__ bias2,
    float* __restrict__ dpart, int ldc, long sA, long sB, long sC) {
  g256_body<1>(A, Bm, Cp, bias, bias2, dpart, ldc, sA, sB, sC);
}

// ============ 256x128 4-phase body — kV / kPV / kW1a / kW1b / kW2 ============
// 16 MFMA per barrier pair; XCD-swizzled. Stage plan per K-tile pair:
// P1: A(t+1)x2; P2: B(t+2) +VMC2; P3: A(t+2)x2; P4: B(t+3) +VMC2.
// OUT_MODE: 0 f32+bias, 1 bf16+bias, 2 bf16 V-transpose+bias,
//           5 PV-normalize (sinv from dpart), 6 bf16 RMW.
__device__ __forceinline__ void readB128(const u16* Bbuf, int wc, int lane, s16x8 (&bfr)[2][2]) {
#pragma unroll
  for (int j = 0; j < 2; ++j)
#pragma unroll
    for (int s = 0; s < 2; ++s)
      bfr[j][s] = lds_frag(Bbuf, wc * 32 + j * 16 + (lane & 15), 4 * s + (lane >> 4));
}
__device__ __forceinline__ void mfma_q128(const s16x8 (&afr)[2][2], const s16x8 (&bfr)[2][2],
                                          f32x4 (&acc)[8][2], int q) {
#pragma unroll
  for (int s = 0; s < 2; ++s)
#pragma unroll
    for (int il = 0; il < 2; ++il)
#pragma unroll
      for (int j = 0; j < 2; ++j)
        acc[q * 2 + il][j] =
            __builtin_amdgcn_mfma_f32_16x16x32_bf16(afr[il][s], bfr[j][s], acc[q * 2 + il][j], 0, 0, 0);
}

template <int OUT_MODE, int HAS_BIAS>
__device__ __forceinline__ void g256n_body(
    const u16* __restrict__ A, const u16* __restrict__ Bm, void* __restrict__ Cp,
    const float* __restrict__ bias, float* __restrict__ dpart,
    int K, int lda, int ldb, int ldc, long sA, long sB, long sC, float scale) {
  __shared__ u16 Al[2][16384];  // 2 x 32 KB: 256 rows x 64 k
  __shared__ u16 Bl[2][8192];   // 2 x 16 KB: 128 rows x 64 k
  __shared__ float sinv[256];
  int bx, by, z;
  swz_decomp(bx, by, z);
  A += (long)z * sA;
  Bm += (long)z * sB;
  const long coff = (long)z * sC;
  const int bm = by * 256, bn = bx * 128;
  const int tid = threadIdx.x;
  const int lane = tid & 63;
  const int w = tid >> 6;
  const int wr = w >> 2, wc = w & 3;  // per-wave 128 rows x 32 cols
  f32x4 acc[8][2] = {};
  const int nt2 = K >> 7;

  auto stageA = [&](u16* Abuf, int h, int kt) {
    const int k0 = kt << 6;
#pragma unroll
    for (int it = 0; it < 2; ++it) {
      int c = w * 128 + it * 64 + lane;
      int row = h * 128 + (c >> 3);
      int j = (c & 7) ^ (row & 7);
      gload_lds16(A + (long)(bm + row) * lda + (k0 + j * 8),
                  Abuf + ((h * 1024 + w * 128 + it * 64) << 3));
    }
  };
  auto stageB = [&](u16* Bbuf, int kt) {
    const int k0 = kt << 6;
#pragma unroll
    for (int it = 0; it < 2; ++it) {
      int c = w * 128 + it * 64 + lane;
      int row = c >> 3;
      int j = (c & 7) ^ (row & 7);
      gload_lds16(Bm + (long)(bn + row) * ldb + (k0 + j * 8),
                  Bbuf + ((w * 128 + it * 64) << 3));
    }
  };

  // prologue: A0<-t0 (2 calls), B0<-t0, B1<-t1; VMC2 leaves B1 in flight
  stageA(Al[0], 0, 0);
  stageA(Al[0], 1, 0);
  stageB(Bl[0], 0);
  stageB(Bl[1], 1);
  VMC2;
  BAR;

  s16x8 bfr[2][2];
  for (int i2 = 0; i2 < nt2; ++i2) {
    const int t = i2 * 2;
    s16x8 afrA[2][2], afrB[2][2];
    // P1: tile t quads 0,1 from buf0; stage A(t+1)
    readB128(Bl[0], wc, lane, bfr);
    readA(Al[0], 0, wr, lane, afrA);
    readA(Al[0], 1, wr, lane, afrB);
    stageA(Al[1], 0, t + 1);
    stageA(Al[1], 1, t + 1);
    BAR;
    __builtin_amdgcn_s_setprio(1);
    mfma_q128(afrA, bfr, acc, 0);
    mfma_q128(afrB, bfr, acc, 1);
    __builtin_amdgcn_s_setprio(0);
    BAR;
    // P2: tile t quads 2,3; stage B(t+2)
    readA(Al[0], 2, wr, lane, afrA);
    readA(Al[0], 3, wr, lane, afrB);
    stageB(Bl[0], t + 2);
    BAR;
    __builtin_amdgcn_s_setprio(1);
    mfma_q128(afrA, bfr, acc, 2);
    mfma_q128(afrB, bfr, acc, 3);
    __builtin_amdgcn_s_setprio(0);
    VMC2;  // leave B0(t+2) in flight
    BAR;
    // P3: tile t+1 quads 0,1 from buf1; stage A(t+2)
    readB128(Bl[1], wc, lane, bfr);
    readA(Al[1], 0, wr, lane, afrA);
    readA(Al[1], 1, wr, lane, afrB);
    stageA(Al[0], 0, t + 2);
    stageA(Al[0], 1, t + 2);
    BAR;
    __builtin_amdgcn_s_setprio(1);
    mfma_q128(afrA, bfr, acc, 0);
    mfma_q128(afrB, bfr, acc, 1);
    __builtin_amdgcn_s_setprio(0);
    BAR;
    // P4: tile t+1 quads 2,3; stage B(t+3)
    readA(Al[1], 2, wr, lane, afrA);
    readA(Al[1], 3, wr, lane, afrB);
    stageB(Bl[1], t + 3);
    BAR;
    __builtin_amdgcn_s_setprio(1);
    mfma_q128(afrA, bfr, acc, 2);
    mfma_q128(afrB, bfr, acc, 3);
    __builtin_amdgcn_s_setprio(0);
    VMC2;  // leave B1(t+3) in flight
    BAR;
  }

  if (OUT_MODE == 5) {
    if (tid < 256) {
      const int row = bm + tid;
      float s = 0.f;
#pragma unroll
      for (int p = 0; p < 32; ++p) s += dpart[((long)z * 32 + p) * S_ + row];
      sinv[tid] = 1.0f / s;
    }
    __syncthreads();
#pragma unroll
    for (int i = 0; i < 8; i++) {
      int mloc = wr * 128 + i * 16 + ((lane >> 4) << 2);
      float inv[4];
#pragma unroll
      for (int r = 0; r < 4; r++) inv[r] = sinv[mloc + r];
#pragma unroll
      for (int j = 0; j < 2; j++) {
        int n = bn + wc * 32 + j * 16 + (lane & 15);
#pragma unroll
        for (int r = 0; r < 4; r++) {
          ((u16a*)Cp)[coff + (long)(bm + mloc + r) * ldc + n] = f2bf(acc[i][j][r] * inv[r]);
        }
      }
    }
    return;
  }
#pragma unroll
  for (int i = 0; i < 8; i++) {
    int mbase = bm + wr * 128 + i * 16 + ((lane >> 4) << 2);
#pragma unroll
    for (int j = 0; j < 2; j++) {
      int n = bn + wc * 32 + j * 16 + (lane & 15);
      float bv = 0.f;
      if (HAS_BIAS) bv = bias[n];
      if (OUT_MODE == 2) {
        ushort4 o;
        o.x = f2bf(acc[i][j][0] * scale + bv);
        o.y = f2bf(acc[i][j][1] * scale + bv);
        o.z = f2bf(acc[i][j][2] * scale + bv);
        o.w = f2bf(acc[i][j][3] * scale + bv);
        long idx = coff + (long)(mbase >> 11) * ((long)D_ * S_) + (long)n * S_ + (mbase & 2047);
        *(ushort4a*)&((u16a*)Cp)[idx] = o;
      } else {
#pragma unroll
        for (int r = 0; r < 4; r++) {
          float v = acc[i][j][r] * scale + bv;
          long idx = coff + (long)(mbase + r) * ldc + n;
          if (OUT_MODE == 1) {
            ((u16a*)Cp)[idx] = f2bf(v);
          } else if (OUT_MODE == 6) {
            u16a* Cb = (u16a*)Cp;
            Cb[idx] = f2bf(bf2f(Cb[idx]) + v);
          } else {
            ((float*)Cp)[idx] = v;
          }
        }
      }
    }
  }
}

#define G256N_ARGS \
    const u16* __restrict__ A, const u16* __restrict__ Bm, void* __restrict__ Cp, \
    const float* __restrict__ bias, float* __restrict__ dpart, \
    int K, int lda, int ldb, int ldc, long sA, long sB, long sC, float scale
#define G256N_FWD A, Bm, Cp, bias, dpart, K, lda, ldb, ldc, sA, sB, sC, scale

__global__ __launch_bounds__(512, 2) void kV(G256N_ARGS)   { g256n_body<2, 1>(G256N_FWD); }
__global__ __launch_bounds__(512, 2) void kPV(G256N_ARGS)  { g256n_body<5, 0>(G256N_FWD); }
__global__ __launch_bounds__(512, 2) void kW1a(G256N_ARGS) { g256n_body<1, 1>(G256N_FWD); }
__global__ __launch_bounds__(512, 2) void kW1b(G256N_ARGS) { g256n_body<6, 0>(G256N_FWD); }
__global__ __launch_bounds__(512, 2) void kW2(G256N_ARGS)  { g256n_body<1, 1>(G256N_FWD); }

// ---------------- LayerNorm over 1024 ----------------
// XBF: base input X in bf16; RBF: residual R in bf16. Y (f32) optional.
template <int XBF, int RBF>
__global__ __launch_bounds__(256) void ln_kernel(
    const void* __restrict__ X, const void* __restrict__ R,
    const float* __restrict__ g, const float* __restrict__ be,
    float* __restrict__ Y, u16* __restrict__ Yb) {
  const long row = blockIdx.x;
  const int t = threadIdx.x, lane = t & 63, w = t >> 6;
  const long base = row * 1024 + t * 4;
  float x0, x1, x2, x3;
  if (XBF) {
    ushort4 xa = *(const ushort4a*)((const u16*)X + base);
    x0 = bf2f(xa.x); x1 = bf2f(xa.y); x2 = bf2f(xa.z); x3 = bf2f(xa.w);
  } else {
    float4 a = *(const float4a*)((const float*)X + base);
    x0 = a.x; x1 = a.y; x2 = a.z; x3 = a.w;
  }
  float r0, r1, r2, r3;
  if (RBF) {
    ushort4 rb = *(const ushort4a*)((const u16*)R + base);
    r0 = bf2f(rb.x); r1 = bf2f(rb.y); r2 = bf2f(rb.z); r3 = bf2f(rb.w);
  } else {
    float4 b = *(const float4a*)((const float*)R + base);
    r0 = b.x; r1 = b.y; r2 = b.z; r3 = b.w;
  }
  float v0 = x0 + r0, v1 = x1 + r1, v2 = x2 + r2, v3 = x3 + r3;
  float s = v0 + v1 + v2 + v3;
  float q = v0 * v0 + v1 * v1 + v2 * v2 + v3 * v3;
#pragma unroll
  for (int o = 32; o > 0; o >>= 1) { s += __shfl_xor(s, o, 64); q += __shfl_xor(q, o, 64); }
  __shared__ float rs[4], rq[4];
  if (lane == 0) { rs[w] = s; rq[w] = q; }
  __syncthreads();
  s = rs[0] + rs[1] + rs[2] + rs[3];
  q = rq[0] + rq[1] + rq[2] + rq[3];
  const float mu = s * (1.f / 1024.f);
  const float var = q * (1.f / 1024.f) - mu * mu;
  const float rstd = rsqrtf(var + 1e-5f);
  float4 gv = *(const float4a*)(g + t * 4);
  float4 bv = *(const float4a*)(be + t * 4);
  float o0 = (v0 - mu) * rstd * gv.x + bv.x;
  float o1 = (v1 - mu) * rstd * gv.y + bv.y;
  float o2 = (v2 - mu) * rstd * gv.z + bv.z;
  float o3 = (v3 - mu) * rstd * gv.w + bv.w;
  if (Y) {
    float4 o4; o4.x = o0; o4.y = o1; o4.z = o2; o4.w = o3;
    *(float4a*)(Y + base) = o4;
  }
  if (Yb) {
    ushort4 ob; ob.x = f2bf(o0); ob.y = f2bf(o1); ob.z = f2bf(o2); ob.w = f2bf(o3);
    *(ushort4a*)(Yb + base) = ob;
  }
}

extern "C" void kernel_launch(void* const* d_in, const int* in_sizes, int n_in,
                              void* d_out, int out_size, void* d_ws, size_t ws_size,
                              hipStream_t stream) {
  const float* x   = (const float*)d_in[0];
  const float* Wq  = (const float*)d_in[1];
  const float* bq  = (const float*)d_in[2];
  const float* Wk  = (const float*)d_in[3];
  const float* bk  = (const float*)d_in[4];
  const float* Wv  = (const float*)d_in[5];
  const float* bv  = (const float*)d_in[6];
  const float* W1  = (const float*)d_in[7];
  const float* b1  = (const float*)d_in[8];
  const float* g1  = (const float*)d_in[9];
  const float* be1 = (const float*)d_in[10];
  const float* W2  = (const float*)d_in[11];
  const float* b2  = (const float*)d_in[12];
  const float* g2  = (const float*)d_in[13];
  const float* be2 = (const float*)d_in[14];
  float* out = (float*)d_out;

  // ---- workspace layout: peak 170,999,808 B (~163 MiB).
  const size_t NEED = 170999808ULL;
  if (ws_size < NEED) return;
  char* ws = (char*)d_ws;
  u16* xb  = (u16*)(ws + 0L);           // 16,777,216  [M][D]
  u16* Wqt = (u16*)(ws + 16777216L);    //  8,388,608  [H][D][D] (out,in)
  u16* Wkt = (u16*)(ws + 25165824L);    //  8,388,608
  u16* Wvt = (u16*)(ws + 33554432L);    //  8,388,608
  u16* W1t = (u16*)(ws + 41943040L);    //  8,388,608  [D][H*D] ldb=4096
  u16* W2t = (u16*)(ws + 50331648L);    //  2,097,152  [D][D]
  u16* Qh  = (u16*)(ws + 52428800L);    // 16,777,216  [M][D]
  u16* Kh  = (u16*)(ws + 69206016L);    // 16,777,216  (contiguous after Qh)
  u16* Vt  = (u16*)(ws + 85983232L);    // 16,777,216  [B][D][S]
  u16* Sbh = (u16*)(ws + 102760448L);   // 33,554,432  [B][S][S] exp-scores
  u16* Cc2 = (u16*)(ws + 136314880L);   // 33,554,432  [M][2048] per-group concat
  float* biasQKV = (float*)(ws + 169869312L); //    49,152
  float* dpart   = (float*)(ws + 169951232L); // 1,048,576  [B][32][S]
  u16* projb = (u16*)out;               // d_out as bf16 scratch [M][D]; LN2 writes last
  u16* yb    = Vt;                      // bf16 LN1 output (Vt dead after head loop)
  u16* z2b16 = Cc2;                     // bf16 W2 output (Cc2 dead after W1b)

  dim3 blk(256), blk512(512);
  {
    long n4 = (long)M_ * D_ / 4;
    hipLaunchKernelGGL(cvt_f32_bf16, dim3(4096), blk, 0, stream, x, xb, n4);
  }
  hipLaunchKernelGGL(tcvt, dim3(32, 32, H_), blk, 0, stream, Wq, Wqt, D_, D_,
                     (long)D_ * D_, (long)D_ * D_);
  hipLaunchKernelGGL(tcvt, dim3(32, 32, H_), blk, 0, stream, Wk, Wkt, D_, D_,
                     (long)D_ * D_, (long)D_ * D_);
  hipLaunchKernelGGL(tcvt, dim3(32, 32, H_), blk, 0, stream, Wv, Wvt, D_, D_,
                     (long)D_ * D_, (long)D_ * D_);
  hipLaunchKernelGGL(tcvt, dim3(32, 128, 1), blk, 0, stream, W1, W1t, H_ * D_, D_, 0L, 0L);
  hipLaunchKernelGGL(tcvt, dim3(32, 32, 1), blk, 0, stream, W2, W2t, D_, D_, 0L, 0L);
  hipLaunchKernelGGL(biascat, dim3(48), blk, 0, stream, bq, bk, bv, biasQKV);

  for (int g = 0; g < 2; ++g) {
    for (int hh = 0; hh < 2; ++hh) {
      const int h = g * 2 + hh;
      const long wo = (long)h * D_ * D_;
      hipLaunchKernelGGL(kQK, dim3(4, 32, 2), blk512, 0, stream,
                         xb, Wqt + wo, Qh, biasQKV + (long)h * D_,
                         biasQKV + 4096 + (long)h * D_, (float*)nullptr,
                         D_, 0L, (long)H_ * D_ * D_, (long)M_ * D_);
      // V: 256x128 4-phase (XCD-swizzled), transposed output [B][D][S]
      hipLaunchKernelGGL(kV, dim3(8, 32, 1), blk512, 0, stream,
                         xb, Wvt + wo, (void*)Vt, biasQKV + 8192 + (long)h * D_,
                         (float*)nullptr, D_, D_, D_, D_, 0L, 0L, 0L, 1.0f);
      hipLaunchKernelGGL(kSC, dim3(8, 8, B_), blk512, 0, stream,
                         Qh, Kh, Sbh, (const float*)nullptr, (const float*)nullptr,
                         dpart, S_, (long)S_ * D_, (long)S_ * D_, (long)S_ * S_);
      // PV: 256x128 4-phase (XCD-swizzled) with in-block dred + normalize
      hipLaunchKernelGGL(kPV, dim3(8, 8, B_), blk512, 0, stream,
                         Sbh, Vt, (void*)(Cc2 + (long)hh * D_), (const float*)nullptr, dpart,
                         S_, S_, S_, 2 * D_,
                         (long)S_ * S_, (long)D_ * S_, (long)S_ * 2 * D_, 1.0f);
    }
    if (g == 0) {
      hipLaunchKernelGGL(kW1a, dim3(8, 32, 1), blk512, 0, stream,
                         Cc2, W1t + (long)g * 2 * D_, (void*)projb, b1, (float*)nullptr,
                         2 * D_, 2 * D_, H_ * D_, D_, 0L, 0L, 0L, 1.0f);
    } else {
      hipLaunchKernelGGL(kW1b, dim3(8, 32, 1), blk512, 0, stream,
                         Cc2, W1t + (long)g * 2 * D_, (void*)projb, (const float*)nullptr,
                         (float*)nullptr, 2 * D_, 2 * D_, H_ * D_, D_, 0L, 0L, 0L, 1.0f);
    }
  }

  // ---- LN1: yb = bf16(LN(x + projb))  (no f32 y stream)
  hipLaunchKernelGGL((ln_kernel<0, 1>), dim3(M_), blk, 0, stream,
                     (const void*)x, (const void*)projb, g1, be1,
                     (float*)nullptr, yb);

  // ---- W2: z2b16 = bf16(yb @ W2t^T + b2)
  hipLaunchKernelGGL(kW2, dim3(8, 32, 1), blk512, 0, stream,
                     yb, W2t, (void*)z2b16, b2, (float*)nullptr,
                     D_, D_, D_, D_, 0L, 0L, 0L, 1.0f);

  // ---- LN2: out = LN(yb + z2b16)   (both residual streams bf16)
  hipLaunchKernelGGL((ln_kernel<1, 1>), dim3(M_), blk, 0, stream,
                     (const void*)yb, (const void*)z2b16, g2, be2,
                     out, (u16*)nullptr);
}